// Round 11
// baseline (191.527 us; speedup 1.0000x reference)
//
#include <hip/hip_runtime.h>
#include <hip/hip_bf16.h>
#include <hip/hip_cooperative_groups.h>

namespace cg = cooperative_groups;

// Problem shape (fixed by setup_inputs): B=2, H=8, T=1024, P=64
#define TDIM 1024
#define PDIM 64
#define BHN  16     // B*H

typedef __bf16 bf16_t;
typedef bf16_t bf16x8 __attribute__((ext_vector_type(8)));
typedef float  floatx4 __attribute__((ext_vector_type(4)));

__device__ __forceinline__ floatx4 mfma16(bf16x8 a, bf16x8 b, floatx4 c) {
    return __builtin_amdgcn_mfma_f32_16x16x32_bf16(a, b, c, 0, 0, 0);
}

// ---------------------------------------------------------------------------
// Single cooperative kernel (R10's prep + featattn fused across a grid sync;
// removes one dispatch + gap, keeps both proven phases byte-identical).
//
// Phase P (producer): block (bh,i), wave w produces 8-row slab = i*8+w of bh:
//   U[bh][t][p]   = bf16( V * exp(K) )              (natural, 128B rows)
//   stats[bh][s][p] = (max K, sum exp2K) over slab  (float2)
//   Kft[bh][q][t] = bf16( exp(K[t][q]) )  — transpose via the wave's own 8
//   rows of the (not-yet-used) Ut[0] LDS buffer; both LDS passes are 2-way
//   bank aliased (free); global write in 16B segments.
// __threadfence + grid.sync()  (R6 lesson: hand-rolled flag sync stalls on
// cross-XCD visibility; the cooperative API is the sanctioned mechanism).
// Phase B (consumer): R10 featattn verbatim — cooperative stats prefix,
// in-block W/den scan, R5-proven dual-slot K-loop with register prefetch
// (prefetch of kt=0/1 moved to after the sync), Ct round-trip, Yred epilogue.
// grid = i*16 + bh (256 blocks of 512 thr = 1 block/CU, co-resident -> safe
// for cooperative launch; LDS 63.3 KB).
// ---------------------------------------------------------------------------
__global__ __launch_bounds__(512) void fused_kernel(
        const float* __restrict__ Q, const float* __restrict__ K,
        const float* __restrict__ V,
        bf16_t* U, bf16_t* Kft, float2* stats,
        float* __restrict__ out) {
    int bh  = blockIdx.x & 15;
    int i   = blockIdx.x >> 4;   // row tile index 0..15
    int tid = threadIdx.x;
    int wave = tid >> 6, lane = tid & 63;
    int lq = lane & 15, qd = lane >> 4;
    int sub = wave & 3;          // substrip: rows [16*sub, 16*sub+16) of tile
    int par = wave >> 2;         // kt parity handled by this wave
    int b = bh >> 3, h = bh & 7;

    __shared__ bf16_t Wt[64][72];
    __shared__ bf16_t Ut[2][64][72];
    __shared__ bf16_t Kt[2][64][72];
    __shared__ __align__(16) char ctyraw[8 * 16 * 72 * 2];  // Ct/Yred/Pt union
    __shared__ float denb[64];
    bf16_t (*Ct)[16][72]  = (bf16_t (*)[16][72])ctyraw;
    float  (*Yred)[16][68] = (float (*)[16][68])ctyraw;
    float2 (*Pt)[64]       = (float2 (*)[64])ctyraw;   // stage-A partials 4KB

    size_t base = (size_t)bh * TDIM * PDIM;
    size_t kftb = (size_t)bh * PDIM * TDIM;
    int row = tid >> 3, c8 = (tid & 7) << 3;   // staging coords: 1 int4/thread

    // ================= phase P: produce U, Kft, stats =================
    {
        int slab = i * 8 + wave;      // 8-row slab index within bh (0..127)
        int t0p  = slab * 8;
        float kq[8], vv[8];
#pragma unroll
        for (int j = 0; j < 8; ++j) {
            kq[j] = K[base + (size_t)(t0p + j) * PDIM + lane];
            vv[j] = V[base + (size_t)(t0p + j) * PDIM + lane];
        }
        float m = -INFINITY, s = 0.f;
#pragma unroll
        for (int j = 0; j < 8; ++j) {
            float e = __expf(kq[j]);
            m = fmaxf(m, kq[j]);
            s += e * e;
            U[base + (size_t)(t0p + j) * PDIM + lane] = (bf16_t)(vv[j] * e);
            Ut[0][wave * 8 + j][lane] = (bf16_t)e;   // wave-private slab
        }
        stats[((size_t)(bh << 7) + slab) * PDIM + lane] = make_float2(m, s);
        // within-wave transpose readback -> coalesced Kft write (16B segs)
        int hi = lane >> 3, tl = lane & 7;
#pragma unroll
        for (int it = 0; it < 8; ++it) {
            int q = it * 8 + hi;
            Kft[kftb + (size_t)q * TDIM + t0p + tl] = Ut[0][wave * 8 + tl][q];
        }
    }
    __threadfence();          // publish U/Kft/stats before the grid barrier
    cg::this_grid().sync();   // all producers done, all XCDs coherent

    // ---- prefetch tiles kt=0,1 (valid only after sync; fly under stage A) --
    int4 pu0 = *(const int4*)(U + base + (size_t)(0 * 64 + row) * PDIM + c8);
    int4 pk0 = *(const int4*)(Kft + kftb + (size_t)row * TDIM + 0 * 64 + c8);
    int4 pu1 = *(const int4*)(U + base + (size_t)(1 * 64 + row) * PDIM + c8);
    int4 pk1 = *(const int4*)(Kft + kftb + (size_t)row * TDIM + 1 * 64 + c8);

    // ---- stage A: W tile + den for rows [i*64 + wave*8, +8) ----
    {
        int t0 = i * 64 + wave * 8;
        // own-row loads first: independent, fly under the stats reduction
        float kr[8], qr[8];
#pragma unroll
        for (int j = 0; j < 8; ++j) {
            kr[j] = K[base + (size_t)(t0 + j) * PDIM + lane];
            qr[j] = Q[base + (size_t)(t0 + j) * PDIM + lane];
        }

        // cooperative partial reduce over chunks [0, 8i):
        // thread (wave,lane) handles residue class {cc = wave mod 8}, col=lane
        const float2* st2 = stats + (size_t)(bh << 7) * PDIM + lane;
        int lim = 8 * i;
        float pm0 = -INFINITY, pm1 = -INFINITY, pm2 = -INFINITY, pm3 = -INFINITY;
        float ps0 = 0.f, ps1 = 0.f, ps2 = 0.f, ps3 = 0.f;
        int cc = wave;
        for (; cc + 24 < lim; cc += 32) {   // 4-way split: depth ~4 L2 rounds
            float2 v0 = st2[(size_t)(cc +  0) * PDIM];
            float2 v1 = st2[(size_t)(cc +  8) * PDIM];
            float2 v2 = st2[(size_t)(cc + 16) * PDIM];
            float2 v3 = st2[(size_t)(cc + 24) * PDIM];
            pm0 = fmaxf(pm0, v0.x); ps0 += v0.y;
            pm1 = fmaxf(pm1, v1.x); ps1 += v1.y;
            pm2 = fmaxf(pm2, v2.x); ps2 += v2.y;
            pm3 = fmaxf(pm3, v3.x); ps3 += v3.y;
        }
        for (; cc < lim; cc += 8) {
            float2 v = st2[(size_t)cc * PDIM];
            pm0 = fmaxf(pm0, v.x); ps0 += v.y;
        }
        Pt[wave][lane] = make_float2(fmaxf(fmaxf(pm0, pm1), fmaxf(pm2, pm3)),
                                     (ps0 + ps1) + (ps2 + ps3));
        __syncthreads();

        float m = -INFINITY, s = 0.f;
#pragma unroll
        for (int g = 0; g < 8; ++g) {
            float2 v = Pt[g][lane];
            m = fmaxf(m, v.x); s += v.y;
        }
        // boundary chunks [8i, 8i+wave): <=7 independent loads
        for (int bc = lim; bc < lim + wave; ++bc) {
            float2 v = st2[(size_t)bc * PDIM];
            m = fmaxf(m, v.x); s += v.y;
        }

        // 8-row seeded scan
        float d[8];
#pragma unroll
        for (int j = 0; j < 8; ++j) {
            m = fmaxf(m, kr[j]);
            float e = __expf(kr[j]);
            s += e * e;                       // inclusive running sum exp(2K)
            float wv = __expf(qr[j] - m);     // inclusive running max
            Wt[wave * 8 + j][lane] = (bf16_t)wv;
            d[j] = wv * s;
        }
        // post-scan reduce: 8 independent butterflies (ILP), not in-loop
#pragma unroll
        for (int off = 32; off > 0; off >>= 1)
#pragma unroll
            for (int j = 0; j < 8; ++j) d[j] += __shfl_xor(d[j], off);
        if (lane == 0) {
#pragma unroll
            for (int j = 0; j < 8; ++j) denb[wave * 8 + j] = d[j];
        }
    }
    __syncthreads();   // Wt/denb ready; Pt region free (reused as Ct)

    // hoist this wave's W A-fragments
    bf16x8 a0 = *(const bf16x8*)&Wt[sub * 16 + lq][qd * 8];
    bf16x8 a1 = *(const bf16x8*)&Wt[sub * 16 + lq][32 + qd * 8];

    floatx4 acc[4];
#pragma unroll
    for (int j = 0; j < 4; ++j) acc[j] = (floatx4){0.f, 0.f, 0.f, 0.f};

    int niter = (i >> 1) + 1;
    for (int kt2 = 0; kt2 < niter; ++kt2) {
        __syncthreads();   // previous compute done reading Ut/Kt
        *(int4*)&Ut[0][row][c8] = pu0;
        *(int4*)&Kt[0][row][c8] = pk0;
        *(int4*)&Ut[1][row][c8] = pu1;
        *(int4*)&Kt[1][row][c8] = pk1;
        // prefetch next super-iteration (loads fly under this one's compute)
        if (kt2 + 1 < niter) {
            int ktn = 2 * kt2 + 2;
            int ktn1 = ktn + 1 > 15 ? 15 : ktn + 1;
            pu0 = *(const int4*)(U + base + (size_t)(ktn * 64 + row) * PDIM + c8);
            pk0 = *(const int4*)(Kft + kftb + (size_t)row * TDIM + ktn * 64 + c8);
            pu1 = *(const int4*)(U + base + (size_t)(ktn1 * 64 + row) * PDIM + c8);
            pk1 = *(const int4*)(Kft + kftb + (size_t)row * TDIM + ktn1 * 64 + c8);
        }
        __syncthreads();   // LDS tiles ready

        int kt = 2 * kt2 + par;
        if (kt <= i) {     // wave-uniform
            // ---- phase 1: C[16 x 64] = W_sub . U_tile^T ----
            floatx4 cc4[4];
#pragma unroll
            for (int j = 0; j < 4; ++j) {
                bf16x8 b0 = *(const bf16x8*)&Ut[par][j * 16 + lq][qd * 8];
                bf16x8 b1 = *(const bf16x8*)&Ut[par][j * 16 + lq][32 + qd * 8];
                floatx4 t = (floatx4){0.f, 0.f, 0.f, 0.f};
                t = mfma16(a0, b0, t);
                t = mfma16(a1, b1, t);
                cc4[j] = t;
            }
            // ---- causal mask + C -> per-wave LDS (C/D: row=qd*4+r, col=lq)
            int trow0 = i * 64 + sub * 16;
#pragma unroll
            for (int j = 0; j < 4; ++j) {
#pragma unroll
                for (int r = 0; r < 4; ++r) {
                    float v = cc4[j][r];
                    if (kt == i && (kt * 64 + j * 16 + lq) > (trow0 + qd * 4 + r))
                        v = 0.f;
                    Ct[wave][qd * 4 + r][j * 16 + lq] = (bf16_t)v;
                }
            }
            // same-wave write->read: compiler lgkmcnt, no barrier
            bf16x8 ca0 = *(const bf16x8*)&Ct[wave][lq][qd * 8];
            bf16x8 ca1 = *(const bf16x8*)&Ct[wave][lq][32 + qd * 8];
            // ---- phase 2: Y_sub += C . Kf_tile ----
#pragma unroll
            for (int j = 0; j < 4; ++j) {
                bf16x8 kb0 = *(const bf16x8*)&Kt[par][j * 16 + lq][qd * 8];
                bf16x8 kb1 = *(const bf16x8*)&Kt[par][j * 16 + lq][32 + qd * 8];
                acc[j] = mfma16(ca0, kb0, acc[j]);
                acc[j] = mfma16(ca1, kb1, acc[j]);
            }
        }
    }

    // ---- cross-parity reduce (Yred aliases Ct; barriers order it) ----
    __syncthreads();
    if (par == 1) {
#pragma unroll
        for (int j = 0; j < 4; ++j)
#pragma unroll
            for (int r = 0; r < 4; ++r)
                Yred[sub][qd * 4 + r][j * 16 + lq] = acc[j][r];
    }
    __syncthreads();
    if (par == 0) {
#pragma unroll
        for (int j = 0; j < 4; ++j) {
#pragma unroll
            for (int r = 0; r < 4; ++r) {
                int trow_l = sub * 16 + qd * 4 + r;
                int tg = i * 64 + trow_l;
                float y = acc[j][r] + Yred[sub][qd * 4 + r][j * 16 + lq];
                y = y / (denb[trow_l] + 1e-6f);
                out[((size_t)b * TDIM + tg) * (8 * PDIM) + h * PDIM + j * 16 + lq] = y;
            }
        }
    }
}

// ---------------------------------------------------------------------------
extern "C" void kernel_launch(void* const* d_in, const int* in_sizes, int n_in,
                              void* d_out, int out_size, void* d_ws, size_t ws_size,
                              hipStream_t stream) {
    const float* Q = (const float*)d_in[0];
    const float* K = (const float*)d_in[1];
    const float* V = (const float*)d_in[2];
    float* out = (float*)d_out;

    bf16_t* Uf   = (bf16_t*)d_ws;                            // 2 MB
    bf16_t* Kft  = Uf + (size_t)BHN * TDIM * PDIM;           // 2 MB
    float2* stats = (float2*)(Kft + (size_t)BHN * TDIM * PDIM);  // 1 MB

    void* args[] = {(void*)&Q, (void*)&K, (void*)&V,
                    (void*)&Uf, (void*)&Kft, (void*)&stats, (void*)&out};
    hipLaunchCooperativeKernel((const void*)fused_kernel,
                               dim3(256), dim3(512), args, 0, stream);
}

// Round 12
// 82.760 us; speedup vs baseline: 2.3142x; 2.3142x over previous
//
#include <hip/hip_runtime.h>
#include <hip/hip_bf16.h>

// Problem shape (fixed by setup_inputs): B=2, H=8, T=1024, P=64
#define TDIM 1024
#define PDIM 64
#define BHN  16     // B*H
#define SCH  8      // stats chunk size (rows)
#define NSC  128    // stats chunks per bh (NSC*SCH == TDIM)

typedef __bf16 bf16_t;
typedef bf16_t bf16x8 __attribute__((ext_vector_type(8)));
typedef float  floatx4 __attribute__((ext_vector_type(4)));

__device__ __forceinline__ floatx4 mfma16(bf16x8 a, bf16x8 b, floatx4 c) {
    return __builtin_amdgcn_mfma_f32_16x16x32_bf16(a, b, c, 0, 0, 0);
}

// ---------------------------------------------------------------------------
// prep: NO scan — elementwise + local transpose only. R12 polish: 128-thread
// blocks (2 waves) -> 2048 waves total = 8 waves/CU (R10 ran 4 waves/CU and
// was latency-bound), each wave owns one 8-row slab = exactly one stats chunk.
//   stats[bh][s][p] = (max K, sum exp2K) over slab s                (float2)
//   U[bh][t][p]     = bf16( V * exp(K) )                            (natural)
//   Kft[bh][q][t]   = bf16( exp(K[t][q]) )  (transpose via shared 16-row
//                     LDS tile; readback 2-way bank-aliased = free; global
//                     writes in 32 B segments)
// grid = BHN*64 blocks (16-row tiles) of 128 thr.
// ---------------------------------------------------------------------------
__global__ __launch_bounds__(128) void prep_kernel(
        const float* __restrict__ K, const float* __restrict__ V,
        bf16_t* __restrict__ U, bf16_t* __restrict__ Kft,
        float2* __restrict__ stats) {
    int bh = blockIdx.x >> 6;
    int c  = blockIdx.x & 63;     // 16-row tile index
    int tid = threadIdx.x;
    int wave = tid >> 6, lane = tid & 63;
    size_t base = (size_t)bh * TDIM * PDIM;
    int t0 = c * 16;
    int r0 = wave * 8;            // this wave's rows within the tile

    float kq[8], vv[8];
#pragma unroll
    for (int j = 0; j < 8; ++j) {
        kq[j] = K[base + (size_t)(t0 + r0 + j) * PDIM + lane];
        vv[j] = V[base + (size_t)(t0 + r0 + j) * PDIM + lane];
    }

    __shared__ bf16_t ek_t[16][PDIM + 4];
    float m = -INFINITY, s = 0.f;
#pragma unroll
    for (int j = 0; j < 8; ++j) {
        float e = __expf(kq[j]);
        m = fmaxf(m, kq[j]);
        s += e * e;
        U[base + (size_t)(t0 + r0 + j) * PDIM + lane] = (bf16_t)(vv[j] * e);
        ek_t[r0 + j][lane] = (bf16_t)e;
    }
    stats[((size_t)(bh << 7) + 2 * c + wave) * PDIM + lane] = make_float2(m, s);
    __syncthreads();

    // transposed write: tid -> (hi = tid>>4 in 0..7, tl = tid&15); 8 q per it
    int hi = tid >> 4, tl = tid & 15;
#pragma unroll
    for (int it = 0; it < 8; ++it) {
        int q = it * 8 + hi;
        Kft[((size_t)bh * PDIM + q) * TDIM + t0 + tl] = ek_t[tl][q];
    }
}

// ---------------------------------------------------------------------------
// featattn (R10 VERBATIM — matched prediction at 84.5 us): in-block stage A
// (W/den, cooperative stats prefix: thread (wave,lane) reduces residue class
// {c = wave mod 8} with 4-way split accumulators; partials via LDS; per-wave
// boundary adds <=7 chunks) + R5-proven dual-slot K-loop (bf16 U/Kft int4
// staging, register prefetch, parity-split waves, Ct round-trip, Yred).
// Block = (bh, i-tile), 512 thr / 8 waves; wave = par*4 + sub.
// grid = i*16 + bh (256 blocks); bh&7 spreads XCDs, 2 bh/XCD fits L2.
// R6/R11 lesson: NEVER fuse across the grid (flag-spin 73 us, grid.sync 106
// us — cross-XCD coherence costs >> the ~4 us dispatch gap).
// ---------------------------------------------------------------------------
__global__ __launch_bounds__(512) void featattn_kernel(
        const float* __restrict__ Q, const float* __restrict__ K,
        const bf16_t* __restrict__ U, const bf16_t* __restrict__ Kft,
        const float2* __restrict__ stats, float* __restrict__ out) {
    int bh  = blockIdx.x & 15;
    int i   = blockIdx.x >> 4;   // row tile index 0..15
    int tid = threadIdx.x;
    int wave = tid >> 6, lane = tid & 63;
    int lq = lane & 15, qd = lane >> 4;
    int sub = wave & 3;          // substrip: rows [16*sub, 16*sub+16) of tile
    int par = wave >> 2;         // kt parity handled by this wave
    int b = bh >> 3, h = bh & 7;

    __shared__ bf16_t Wt[64][72];
    __shared__ bf16_t Ut[2][64][72];
    __shared__ bf16_t Kt[2][64][72];
    __shared__ __align__(16) char ctyraw[8 * 16 * 72 * 2];  // Ct/Yred/Pt union
    __shared__ float denb[64];
    bf16_t (*Ct)[16][72]  = (bf16_t (*)[16][72])ctyraw;
    float  (*Yred)[16][68] = (float (*)[16][68])ctyraw;
    float2 (*Pt)[64]       = (float2 (*)[64])ctyraw;   // stage-A partials 4KB

    size_t base = (size_t)bh * TDIM * PDIM;
    size_t kftb = (size_t)bh * PDIM * TDIM;
    int row = tid >> 3, c8 = (tid & 7) << 3;   // staging coords: 1 int4/thread

    // ---- prefetch tiles kt=0,1 (always in-bounds; fly under stage A) ----
    int4 pu0 = *(const int4*)(U + base + (size_t)(0 * 64 + row) * PDIM + c8);
    int4 pk0 = *(const int4*)(Kft + kftb + (size_t)row * TDIM + 0 * 64 + c8);
    int4 pu1 = *(const int4*)(U + base + (size_t)(1 * 64 + row) * PDIM + c8);
    int4 pk1 = *(const int4*)(Kft + kftb + (size_t)row * TDIM + 1 * 64 + c8);

    // ---- stage A: W tile + den for rows [i*64 + wave*8, +8) ----
    {
        int t0 = i * 64 + wave * 8;
        // own-row loads first: independent, fly under the stats reduction
        float kr[8], qr[8];
#pragma unroll
        for (int j = 0; j < 8; ++j) {
            kr[j] = K[base + (size_t)(t0 + j) * PDIM + lane];
            qr[j] = Q[base + (size_t)(t0 + j) * PDIM + lane];
        }

        // cooperative partial reduce over chunks [0, 8i):
        // thread (wave,lane) handles residue class {cc = wave mod 8}, col=lane
        const float2* st2 = stats + (size_t)(bh << 7) * PDIM + lane;
        int lim = 8 * i;
        float pm0 = -INFINITY, pm1 = -INFINITY, pm2 = -INFINITY, pm3 = -INFINITY;
        float ps0 = 0.f, ps1 = 0.f, ps2 = 0.f, ps3 = 0.f;
        int cc = wave;
        for (; cc + 24 < lim; cc += 32) {   // 4-way split: depth ~4 L2 rounds
            float2 v0 = st2[(size_t)(cc +  0) * PDIM];
            float2 v1 = st2[(size_t)(cc +  8) * PDIM];
            float2 v2 = st2[(size_t)(cc + 16) * PDIM];
            float2 v3 = st2[(size_t)(cc + 24) * PDIM];
            pm0 = fmaxf(pm0, v0.x); ps0 += v0.y;
            pm1 = fmaxf(pm1, v1.x); ps1 += v1.y;
            pm2 = fmaxf(pm2, v2.x); ps2 += v2.y;
            pm3 = fmaxf(pm3, v3.x); ps3 += v3.y;
        }
        for (; cc < lim; cc += 8) {
            float2 v = st2[(size_t)cc * PDIM];
            pm0 = fmaxf(pm0, v.x); ps0 += v.y;
        }
        Pt[wave][lane] = make_float2(fmaxf(fmaxf(pm0, pm1), fmaxf(pm2, pm3)),
                                     (ps0 + ps1) + (ps2 + ps3));
        __syncthreads();

        float m = -INFINITY, s = 0.f;
#pragma unroll
        for (int g = 0; g < 8; ++g) {
            float2 v = Pt[g][lane];
            m = fmaxf(m, v.x); s += v.y;
        }
        // boundary chunks [8i, 8i+wave): <=7 independent loads
        for (int bc = lim; bc < lim + wave; ++bc) {
            float2 v = st2[(size_t)bc * PDIM];
            m = fmaxf(m, v.x); s += v.y;
        }

        // 8-row seeded scan
        float d[8];
#pragma unroll
        for (int j = 0; j < 8; ++j) {
            m = fmaxf(m, kr[j]);
            float e = __expf(kr[j]);
            s += e * e;                       // inclusive running sum exp(2K)
            float wv = __expf(qr[j] - m);     // inclusive running max
            Wt[wave * 8 + j][lane] = (bf16_t)wv;
            d[j] = wv * s;
        }
        // post-scan reduce: 8 independent butterflies (ILP), not in-loop
#pragma unroll
        for (int off = 32; off > 0; off >>= 1)
#pragma unroll
            for (int j = 0; j < 8; ++j) d[j] += __shfl_xor(d[j], off);
        if (lane == 0) {
#pragma unroll
            for (int j = 0; j < 8; ++j) denb[wave * 8 + j] = d[j];
        }
    }
    __syncthreads();   // Wt/denb ready; Pt region free (reused as Ct)

    // hoist this wave's W A-fragments
    bf16x8 a0 = *(const bf16x8*)&Wt[sub * 16 + lq][qd * 8];
    bf16x8 a1 = *(const bf16x8*)&Wt[sub * 16 + lq][32 + qd * 8];

    floatx4 acc[4];
#pragma unroll
    for (int j = 0; j < 4; ++j) acc[j] = (floatx4){0.f, 0.f, 0.f, 0.f};

    int niter = (i >> 1) + 1;
    for (int kt2 = 0; kt2 < niter; ++kt2) {
        __syncthreads();   // previous compute done reading Ut/Kt
        *(int4*)&Ut[0][row][c8] = pu0;
        *(int4*)&Kt[0][row][c8] = pk0;
        *(int4*)&Ut[1][row][c8] = pu1;
        *(int4*)&Kt[1][row][c8] = pk1;
        // prefetch next super-iteration (loads fly under this one's compute)
        if (kt2 + 1 < niter) {
            int ktn = 2 * kt2 + 2;
            int ktn1 = ktn + 1 > 15 ? 15 : ktn + 1;
            pu0 = *(const int4*)(U + base + (size_t)(ktn * 64 + row) * PDIM + c8);
            pk0 = *(const int4*)(Kft + kftb + (size_t)row * TDIM + ktn * 64 + c8);
            pu1 = *(const int4*)(U + base + (size_t)(ktn1 * 64 + row) * PDIM + c8);
            pk1 = *(const int4*)(Kft + kftb + (size_t)row * TDIM + ktn1 * 64 + c8);
        }
        __syncthreads();   // LDS tiles ready

        int kt = 2 * kt2 + par;
        if (kt <= i) {     // wave-uniform
            // ---- phase 1: C[16 x 64] = W_sub . U_tile^T ----
            floatx4 cc4[4];
#pragma unroll
            for (int j = 0; j < 4; ++j) {
                bf16x8 b0 = *(const bf16x8*)&Ut[par][j * 16 + lq][qd * 8];
                bf16x8 b1 = *(const bf16x8*)&Ut[par][j * 16 + lq][32 + qd * 8];
                floatx4 t = (floatx4){0.f, 0.f, 0.f, 0.f};
                t = mfma16(a0, b0, t);
                t = mfma16(a1, b1, t);
                cc4[j] = t;
            }
            // ---- causal mask + C -> per-wave LDS (C/D: row=qd*4+r, col=lq)
            int trow0 = i * 64 + sub * 16;
#pragma unroll
            for (int j = 0; j < 4; ++j) {
#pragma unroll
                for (int r = 0; r < 4; ++r) {
                    float v = cc4[j][r];
                    if (kt == i && (kt * 64 + j * 16 + lq) > (trow0 + qd * 4 + r))
                        v = 0.f;
                    Ct[wave][qd * 4 + r][j * 16 + lq] = (bf16_t)v;
                }
            }
            // same-wave write->read: compiler lgkmcnt, no barrier
            bf16x8 ca0 = *(const bf16x8*)&Ct[wave][lq][qd * 8];
            bf16x8 ca1 = *(const bf16x8*)&Ct[wave][lq][32 + qd * 8];
            // ---- phase 2: Y_sub += C . Kf_tile ----
#pragma unroll
            for (int j = 0; j < 4; ++j) {
                bf16x8 kb0 = *(const bf16x8*)&Kt[par][j * 16 + lq][qd * 8];
                bf16x8 kb1 = *(const bf16x8*)&Kt[par][j * 16 + lq][32 + qd * 8];
                acc[j] = mfma16(ca0, kb0, acc[j]);
                acc[j] = mfma16(ca1, kb1, acc[j]);
            }
        }
    }

    // ---- cross-parity reduce (Yred aliases Ct; barriers order it) ----
    __syncthreads();
    if (par == 1) {
#pragma unroll
        for (int j = 0; j < 4; ++j)
#pragma unroll
            for (int r = 0; r < 4; ++r)
                Yred[sub][qd * 4 + r][j * 16 + lq] = acc[j][r];
    }
    __syncthreads();
    if (par == 0) {
#pragma unroll
        for (int j = 0; j < 4; ++j) {
#pragma unroll
            for (int r = 0; r < 4; ++r) {
                int trow_l = sub * 16 + qd * 4 + r;
                int tg = i * 64 + trow_l;
                float y = acc[j][r] + Yred[sub][qd * 4 + r][j * 16 + lq];
                y = y / (denb[trow_l] + 1e-6f);
                out[((size_t)b * TDIM + tg) * (8 * PDIM) + h * PDIM + j * 16 + lq] = y;
            }
        }
    }
}

// ---------------------------------------------------------------------------
extern "C" void kernel_launch(void* const* d_in, const int* in_sizes, int n_in,
                              void* d_out, int out_size, void* d_ws, size_t ws_size,
                              hipStream_t stream) {
    const float* Q = (const float*)d_in[0];
    const float* K = (const float*)d_in[1];
    const float* V = (const float*)d_in[2];
    float* out = (float*)d_out;

    bf16_t* Uf   = (bf16_t*)d_ws;                            // 2 MB
    bf16_t* Kft  = Uf + (size_t)BHN * TDIM * PDIM;           // 2 MB
    float2* stats = (float2*)(Kft + (size_t)BHN * TDIM * PDIM);  // 1 MB

    prep_kernel<<<BHN * 64, 128, 0, stream>>>(K, V, Uf, Kft, stats);
    featattn_kernel<<<256, 512, 0, stream>>>(Q, K, Uf, Kft, stats, out);
}